// Round 1
// baseline (661.340 us; speedup 1.0000x reference)
//
#include <hip/hip_runtime.h>
#include <hip/hip_fp16.h>

// (V, D, H, L, E) = (50000, 128, 128, 4, 160000)
#define V_NODES 50000
#define NEDGE   160000

typedef __bf16 bf16;
typedef __attribute__((ext_vector_type(8))) __bf16 bf16x8;
typedef __attribute__((ext_vector_type(4))) __bf16 bf16x4;
typedef __attribute__((ext_vector_type(4))) float  f32x4;

__device__ __forceinline__ int clampV(int n) {
  unsigned u = (unsigned)n;
  return (int)(u < (unsigned)V_NODES ? u : (unsigned)(V_NODES - 1));
}

// ---------------- prep kernels: fp32 -> bf16 (weights transposed) ----------

__global__ __launch_bounds__(256) void prep_emb_k(const float* __restrict__ in,
                                                  bf16* __restrict__ out) {
  int i = blockIdx.x * 256 + threadIdx.x;
  float4 v = ((const float4*)in)[i];
  bf16x4 o = {(bf16)v.x, (bf16)v.y, (bf16)v.z, (bf16)v.w};
  *(bf16x4*)(out + (size_t)i * 4) = o;
}

__global__ __launch_bounds__(256) void prep_w1_k(const float* __restrict__ in,
                                                 bf16* __restrict__ out) {
  int idx = blockIdx.x * 256 + threadIdx.x;         // 262144
  int n = idx & 127, k = (idx >> 7) & 255, g = idx >> 15;
  out[(((g << 7) + n) << 8) + k] = (bf16)in[idx];
}

__global__ __launch_bounds__(256) void prep_w2_k(const float* __restrict__ in,
                                                 bf16* __restrict__ out) {
  int idx = blockIdx.x * 256 + threadIdx.x;         // 131072
  int n = idx & 127, k = (idx >> 7) & 127, g = idx >> 14;
  out[(((g << 7) + n) << 7) + k] = (bf16)in[idx];
}

__global__ __launch_bounds__(256) void relu_k(float* __restrict__ out) {
  int i = blockIdx.x * 256 + threadIdx.x;
  float4 v = ((float4*)out)[i];
  v.x = fmaxf(v.x, 0.f); v.y = fmaxf(v.y, 0.f);
  v.z = fmaxf(v.z, 0.f); v.w = fmaxf(v.w, 0.f);
  ((float4*)out)[i] = v;
}

// ---- final pass for f16-accumulator path: out = relu((float)acc) ----------
// 6,400,000 halfs; one thread converts 8 halfs (16B load, 32B store).

__global__ __launch_bounds__(256) void cvt_relu_k(const __half* __restrict__ acc,
                                                  float* __restrict__ out) {
  int i = blockIdx.x * 256 + threadIdx.x;           // 0..799999
  uint4 u = ((const uint4*)acc)[i];
  union { uint4 u; __half2 h[4]; } cv; cv.u = u;
  float4 o0, o1;
  o0.x = fmaxf(__low2float(cv.h[0]), 0.f);  o0.y = fmaxf(__high2float(cv.h[0]), 0.f);
  o0.z = fmaxf(__low2float(cv.h[1]), 0.f);  o0.w = fmaxf(__high2float(cv.h[1]), 0.f);
  o1.x = fmaxf(__low2float(cv.h[2]), 0.f);  o1.y = fmaxf(__high2float(cv.h[2]), 0.f);
  o1.z = fmaxf(__low2float(cv.h[3]), 0.f);  o1.w = fmaxf(__high2float(cv.h[3]), 0.f);
  ((float4*)out)[2 * i]     = o0;
  ((float4*)out)[2 * i + 1] = o1;
}

// ---------------- edge kernel, pk-f16 atomic accumulation ------------------
// Identical GEMM1/GEMM2 structure to the proven edge_k; only the writeback
// changes: lane-pairs (l15, l15^1) exchange values via __shfl_xor(.,1) and
// issue ONE global_atomic_pk_add_f16 per dim-pair. Even lanes flush MFMA
// rows r=0,1; odd lanes r=2,3 -> 16 pk atomics/lane/tile vs 32 f32 atomics.

__global__ __launch_bounds__(256) void edge_f16_k(
    const bf16* __restrict__ embB,
    const int* __restrict__ a0, const int* __restrict__ a1,
    const int* __restrict__ a2, const int* __restrict__ a3,
    const bf16* __restrict__ w1t, const bf16* __restrict__ w2t,
    __half* __restrict__ accH) {

  __shared__ __attribute__((aligned(16))) bf16 w1_lds[128 * 256];
  __shared__ __attribute__((aligned(16))) bf16 h_lds[64 * 128];

  const int tid = threadIdx.x;
  const int g  = blockIdx.x >> 6;
  const int bs = blockIdx.x & 63;
  const int l = g >> 1, ep = g & 1;
  const int* __restrict__ adj = (l == 0) ? a0 : (l == 1) ? a1 : (l == 2) ? a2 : a3;

  {
    const uint4* w1g = (const uint4*)(w1t + (size_t)g * 128 * 256);
    #pragma unroll
    for (int i = 0; i < 16; ++i) {
      int j = i * 256 + tid;
      int n = j >> 5, c = j & 31;
      *(uint4*)(&w1_lds[n * 256 + ((c ^ (n & 7)) << 3)]) = w1g[j];
    }
  }
  __syncthreads();

  const int w    = tid >> 6;
  const int lane = tid & 63;
  const int wr = w >> 1, wc = w & 1;
  const int l15 = lane & 15, q = lane >> 4;
  const int par = l15 & 1;
  const bf16* __restrict__ w2g = w2t + (size_t)g * 128 * 128;

  for (int t = bs; t < 2500; t += 64) {
    const int ebase = t * 64;
    int2 pr0 = ((const int2*)adj)[ebase + 32 * wr + l15];
    int2 pr1 = ((const int2*)adj)[ebase + 32 * wr + 16 + l15];
    pr0.x = clampV(pr0.x); pr0.y = clampV(pr0.y);
    pr1.x = clampV(pr1.x); pr1.y = clampV(pr1.y);

    f32x4 acc[2][4] = {};
    #pragma unroll
    for (int kb = 0; kb < 8; ++kb) {
      const int k = kb * 32 + q * 8;
      const int klo = k & 127;
      const int n0 = (kb < 4) ? pr0.x : pr0.y;
      const int n1 = (kb < 4) ? pr1.x : pr1.y;
      bf16x8 a[2], b[4];
      a[0] = *(const bf16x8*)(embB + (size_t)n0 * 128 + klo);
      a[1] = *(const bf16x8*)(embB + (size_t)n1 * 128 + klo);
      const int csw = ((kb << 2) + q);
      #pragma unroll
      for (int nt = 0; nt < 4; ++nt) {
        int n = 64 * wc + 16 * nt + l15;
        b[nt] = *(const bf16x8*)(&w1_lds[n * 256 + ((csw ^ (l15 & 7)) << 3)]);
      }
      #pragma unroll
      for (int mt = 0; mt < 2; ++mt)
        #pragma unroll
        for (int nt = 0; nt < 4; ++nt)
          acc[mt][nt] = __builtin_amdgcn_mfma_f32_16x16x32_bf16(a[mt], b[nt], acc[mt][nt], 0, 0, 0);
    }

    __syncthreads();
    #pragma unroll
    for (int mt = 0; mt < 2; ++mt)
      #pragma unroll
      for (int nt = 0; nt < 4; ++nt)
        #pragma unroll
        for (int r = 0; r < 4; ++r) {
          float v = acc[mt][nt][r];
          v = v > 0.f ? v : 0.f;
          int row = 32 * wr + 16 * mt + 4 * q + r;
          int col = 64 * wc + 16 * nt + l15;
          int c = col >> 3;
          h_lds[row * 128 + (((c ^ (row & 7)) << 3) | (col & 7))] = (bf16)v;
        }
    __syncthreads();

    f32x4 acc2[2][4] = {};
    #pragma unroll
    for (int kb = 0; kb < 4; ++kb) {
      const int k = kb * 32 + q * 8;
      const int csw = (kb << 2) + q;
      bf16x8 a[2], b[4];
      #pragma unroll
      for (int mt = 0; mt < 2; ++mt) {
        int row = 32 * wr + 16 * mt + l15;
        a[mt] = *(const bf16x8*)(&h_lds[row * 128 + ((csw ^ (row & 7)) << 3)]);
      }
      #pragma unroll
      for (int nt = 0; nt < 4; ++nt) {
        int n = 64 * wc + 16 * nt + l15;
        b[nt] = *(const bf16x8*)(w2g + n * 128 + k);
      }
      #pragma unroll
      for (int mt = 0; mt < 2; ++mt)
        #pragma unroll
        for (int nt = 0; nt < 4; ++nt)
          acc2[mt][nt] = __builtin_amdgcn_mfma_f32_16x16x32_bf16(a[mt], b[nt], acc2[mt][nt], 0, 0, 0);
    }

    // ---- pk-f16 atomic writeback: 16 pk atomics/lane vs 32 f32 atomics ----
    // Lane handles MFMA rows r = 2*par, 2*par+1 of each mt-block, for the
    // dim-pair (col&~1, col|1). Neighbor values come via __shfl_xor(.,1).
    #pragma unroll
    for (int mt = 0; mt < 2; ++mt) {
      const int rbase = ebase + 32 * wr + 16 * mt + 4 * q + 2 * par;
      int2 prA = ((const int2*)adj)[rbase];
      int2 prB = ((const int2*)adj)[rbase + 1];
      const int nodeA = clampV(ep ? prA.y : prA.x);
      const int nodeB = clampV(ep ? prB.y : prB.x);
      __half* pA = accH + (size_t)nodeA * 128 + 64 * wc + (l15 & ~1);
      __half* pB = accH + (size_t)nodeB * 128 + 64 * wc + (l15 & ~1);
      #pragma unroll
      for (int nt = 0; nt < 4; ++nt) {
        f32x4 a = acc2[mt][nt];
        // symmetric exchange: even lane sends a[2],a[3]; odd sends a[0],a[1]
        float s0 = par ? a[0] : a[2];
        float s1 = par ? a[1] : a[3];
        float x0 = __shfl_xor(s0, 1);
        float x1 = __shfl_xor(s1, 1);
        // even lane: rows r=0,1 -> (own, neighbor); odd: rows r=2,3 -> (neighbor, own)
        float lo0 = par ? x0 : a[0];
        float hi0 = par ? a[2] : x0;
        float lo1 = par ? x1 : a[1];
        float hi1 = par ? a[3] : x1;
        __half2 vA = __halves2half2(__float2half_rn(lo0), __float2half_rn(hi0));
        __half2 vB = __halves2half2(__float2half_rn(lo1), __float2half_rn(hi1));
        unsafeAtomicAdd((__half2*)(pA + 16 * nt), vA);
        unsafeAtomicAdd((__half2*)(pB + 16 * nt), vB);
      }
    }
  }
}

// ---------------- fallback edge kernel (round-4, proven) -------------------

__global__ __launch_bounds__(256) void edge_k(
    const bf16* __restrict__ embB,
    const int* __restrict__ a0, const int* __restrict__ a1,
    const int* __restrict__ a2, const int* __restrict__ a3,
    const bf16* __restrict__ w1t, const bf16* __restrict__ w2t,
    float* __restrict__ out) {

  __shared__ __attribute__((aligned(16))) bf16 w1_lds[128 * 256];
  __shared__ __attribute__((aligned(16))) bf16 h_lds[64 * 128];

  const int tid = threadIdx.x;
  const int g  = blockIdx.x >> 6;
  const int bs = blockIdx.x & 63;
  const int l = g >> 1, ep = g & 1;
  const int* __restrict__ adj = (l == 0) ? a0 : (l == 1) ? a1 : (l == 2) ? a2 : a3;

  {
    const uint4* w1g = (const uint4*)(w1t + (size_t)g * 128 * 256);
    #pragma unroll
    for (int i = 0; i < 16; ++i) {
      int j = i * 256 + tid;
      int n = j >> 5, c = j & 31;
      *(uint4*)(&w1_lds[n * 256 + ((c ^ (n & 7)) << 3)]) = w1g[j];
    }
  }
  __syncthreads();

  const int w    = tid >> 6;
  const int lane = tid & 63;
  const int wr = w >> 1, wc = w & 1;
  const int l15 = lane & 15, q = lane >> 4;
  const bf16* __restrict__ w2g = w2t + (size_t)g * 128 * 128;

  for (int t = bs; t < 2500; t += 64) {
    const int ebase = t * 64;
    int2 pr0 = ((const int2*)adj)[ebase + 32 * wr + l15];
    int2 pr1 = ((const int2*)adj)[ebase + 32 * wr + 16 + l15];
    pr0.x = clampV(pr0.x); pr0.y = clampV(pr0.y);
    pr1.x = clampV(pr1.x); pr1.y = clampV(pr1.y);

    f32x4 acc[2][4] = {};
    #pragma unroll
    for (int kb = 0; kb < 8; ++kb) {
      const int k = kb * 32 + q * 8;
      const int klo = k & 127;
      const int n0 = (kb < 4) ? pr0.x : pr0.y;
      const int n1 = (kb < 4) ? pr1.x : pr1.y;
      bf16x8 a[2], b[4];
      a[0] = *(const bf16x8*)(embB + (size_t)n0 * 128 + klo);
      a[1] = *(const bf16x8*)(embB + (size_t)n1 * 128 + klo);
      const int csw = ((kb << 2) + q);
      #pragma unroll
      for (int nt = 0; nt < 4; ++nt) {
        int n = 64 * wc + 16 * nt + l15;
        b[nt] = *(const bf16x8*)(&w1_lds[n * 256 + ((csw ^ (l15 & 7)) << 3)]);
      }
      #pragma unroll
      for (int mt = 0; mt < 2; ++mt)
        #pragma unroll
        for (int nt = 0; nt < 4; ++nt)
          acc[mt][nt] = __builtin_amdgcn_mfma_f32_16x16x32_bf16(a[mt], b[nt], acc[mt][nt], 0, 0, 0);
    }

    __syncthreads();
    #pragma unroll
    for (int mt = 0; mt < 2; ++mt)
      #pragma unroll
      for (int nt = 0; nt < 4; ++nt)
        #pragma unroll
        for (int r = 0; r < 4; ++r) {
          float v = acc[mt][nt][r];
          v = v > 0.f ? v : 0.f;
          int row = 32 * wr + 16 * mt + 4 * q + r;
          int col = 64 * wc + 16 * nt + l15;
          int c = col >> 3;
          h_lds[row * 128 + (((c ^ (row & 7)) << 3) | (col & 7))] = (bf16)v;
        }
    __syncthreads();

    f32x4 acc2[2][4] = {};
    #pragma unroll
    for (int kb = 0; kb < 4; ++kb) {
      const int k = kb * 32 + q * 8;
      const int csw = (kb << 2) + q;
      bf16x8 a[2], b[4];
      #pragma unroll
      for (int mt = 0; mt < 2; ++mt) {
        int row = 32 * wr + 16 * mt + l15;
        a[mt] = *(const bf16x8*)(&h_lds[row * 128 + ((csw ^ (row & 7)) << 3)]);
      }
      #pragma unroll
      for (int nt = 0; nt < 4; ++nt) {
        int n = 64 * wc + 16 * nt + l15;
        b[nt] = *(const bf16x8*)(w2g + n * 128 + k);
      }
      #pragma unroll
      for (int mt = 0; mt < 2; ++mt)
        #pragma unroll
        for (int nt = 0; nt < 4; ++nt)
          acc2[mt][nt] = __builtin_amdgcn_mfma_f32_16x16x32_bf16(a[mt], b[nt], acc2[mt][nt], 0, 0, 0);
    }

    #pragma unroll
    for (int mt = 0; mt < 2; ++mt)
      #pragma unroll
      for (int r = 0; r < 4; ++r) {
        int row = 32 * wr + 16 * mt + 4 * q + r;
        int2 pr = ((const int2*)adj)[ebase + row];
        int node = clampV(ep ? pr.y : pr.x);
        float* basep = out + (size_t)node * 128 + 64 * wc + l15;
        #pragma unroll
        for (int nt = 0; nt < 4; ++nt)
          unsafeAtomicAdd(basep + 16 * nt, acc2[mt][nt][r]);
      }
  }
}

// ---------------- host launch ----------------------------------------------

extern "C" void kernel_launch(void* const* d_in, const int* in_sizes, int n_in,
                              void* d_out, int out_size, void* d_ws, size_t ws_size,
                              hipStream_t stream) {
  const float* emb = (const float*)d_in[0];
  const int* a0 = (const int*)d_in[1];
  const int* a1 = (const int*)d_in[2];
  const int* a2 = (const int*)d_in[3];
  const int* a3 = (const int*)d_in[4];
  const float* W1 = (const float*)d_in[5];
  const float* W2 = (const float*)d_in[6];
  float* out = (float*)d_out;

  char* ws = (char*)d_ws;
  bf16*   embB = (bf16*)(ws);                    // 12,800,000
  bf16*   w1t  = (bf16*)(ws + 12800000);         //    524,288
  bf16*   w2t  = (bf16*)(ws + 13324288);         //    262,144
  __half* accH = (__half*)(ws + 13586432);       // 12,800,000 (f16 accumulator)
  const size_t need_f16 = 26386432;

  prep_emb_k<<<6250, 256, 0, stream>>>(emb, embB);
  prep_w1_k<<<1024, 256, 0, stream>>>(W1, w1t);
  prep_w2_k<<<512, 256, 0, stream>>>(W2, w2t);

  if (ws_size >= need_f16) {
    // pk-f16 atomic accumulation: halves atomic ops + bytes vs f32 path
    hipMemsetAsync(accH, 0, 12800000, stream);
    edge_f16_k<<<512, 256, 0, stream>>>(embB, a0, a1, a2, a3, w1t, w2t, accH);
    cvt_relu_k<<<3125, 256, 0, stream>>>(accH, out);
  } else {
    hipMemsetAsync(d_out, 0, (size_t)V_NODES * 128 * sizeof(float), stream);
    edge_k<<<512, 256, 0, stream>>>(embB, a0, a1, a2, a3, w1t, w2t, out);
    relu_k<<<6250, 256, 0, stream>>>(out);
  }
}